// Round 1
// baseline (5033.440 us; speedup 1.0000x reference)
//
#include <hip/hip_runtime.h>
#include <cstdint>
#include <cstddef>

typedef unsigned int u32;
typedef _Float16 f16;
typedef f16 f16x2 __attribute__((ext_vector_type(2)));

constexpr int nB = 512, nS = 256, nD = 64, nH = 128, nG = 512;

// ---------------- workspace layout (bytes) ----------------
constexpr size_t OFF_W0   = 0;                                   // [512][192] f16 enc0 Wih|Whh
constexpr size_t OFF_W1   = OFF_W0   + (size_t)512*192*2;        // [512][256] f16 enc1 Wih|Whh
constexpr size_t OFF_WD0A = OFF_W1   + (size_t)512*256*2;        // [512][64]  f16 dec Wih0
constexpr size_t OFF_WD0B = OFF_WD0A + (size_t)512*64*2;         // [512][128] f16 dec Whh0
constexpr size_t OFF_WD1  = OFF_WD0B + (size_t)512*128*2;        // [512][256] f16 dec Wih1|Whh1
constexpr size_t OFF_FC   = OFF_WD1  + (size_t)512*256*2;        // [64][128]  f16 fc_W
constexpr size_t OFF_QKVW = OFF_FC   + (size_t)64*128*2;         // [3][128][128] f16 Qw,Kw,Vw
constexpr size_t OFF_B0   = OFF_QKVW + (size_t)3*128*128*2;      // [512] f32 (bih+bhh)
constexpr size_t OFF_B1   = OFF_B0   + 512*4;
constexpr size_t OFF_BD0  = OFF_B1   + 512*4;
constexpr size_t OFF_BD1  = OFF_BD0  + 512*4;
constexpr size_t OFF_HF0  = OFF_BD1  + 512*4;                    // [B][H] f32 enc L0 final h
constexpr size_t OFF_CF0  = OFF_HF0  + (size_t)nB*nH*4;
constexpr size_t OFF_HF1  = OFF_CF0  + (size_t)nB*nH*4;
constexpr size_t OFF_CF1  = OFF_HF1  + (size_t)nB*nH*4;
constexpr size_t OFF_HINIT= OFF_CF1  + (size_t)nB*nH*4;          // [2][B][H] f32 (hfin + proj)
constexpr size_t OFF_Y0   = OFF_HINIT+ (size_t)2*nB*nH*4;        // [S][B][H] f16
constexpr size_t OFF_Y1   = OFF_Y0   + (size_t)nS*nB*nH*2;       // [S][B][H] f16
constexpr size_t OFF_Q    = OFF_Y1   + (size_t)nS*nB*nH*2;       // [B][S][H] f16
constexpr size_t OFF_K    = OFF_Q    + (size_t)nB*nS*nH*2;
constexpr size_t OFF_V    = OFF_K    + (size_t)nB*nS*nH*2;
constexpr size_t WS_NEED  = OFF_V    + (size_t)nB*nS*nH*2;       // ~170 MB

// ---------------- helpers ----------------
__device__ __forceinline__ float fdot2u(u32 w, u32 x, float acc) {
#if defined(__has_builtin)
#if __has_builtin(__builtin_amdgcn_fdot2)
    return __builtin_amdgcn_fdot2(__builtin_bit_cast(f16x2, w),
                                  __builtin_bit_cast(f16x2, x), acc, false);
#else
    const f16x2 a = __builtin_bit_cast(f16x2, w), b = __builtin_bit_cast(f16x2, x);
    return acc + (float)a.x * (float)b.x + (float)a.y * (float)b.y;
#endif
#else
    const f16x2 a = __builtin_bit_cast(f16x2, w), b = __builtin_bit_cast(f16x2, x);
    return acc + (float)a.x * (float)b.x + (float)a.y * (float)b.y;
#endif
}

__device__ __forceinline__ float sigm_f(float x) {
    return __builtin_amdgcn_rcpf(1.0f + __expf(-x));
}
__device__ __forceinline__ float tanh_f(float x) {
    // 1 - 2/(e^{2x}+1); exp overflow/underflow saturate correctly to +-1
    return 1.0f - 2.0f * __builtin_amdgcn_rcpf(__expf(2.0f * x) + 1.0f);
}

// ---------------- K0: weight pack/convert (fp32 -> fp16, bias fuse) ----------------
__global__ void prep_kernel(
    const float* __restrict__ Wih0, const float* __restrict__ Whh0,
    const float* __restrict__ bih0, const float* __restrict__ bhh0,
    const float* __restrict__ Wih1, const float* __restrict__ Whh1,
    const float* __restrict__ bih1, const float* __restrict__ bhh1,
    const float* __restrict__ dWih0, const float* __restrict__ dWhh0,
    const float* __restrict__ dbih0, const float* __restrict__ dbhh0,
    const float* __restrict__ dWih1, const float* __restrict__ dWhh1,
    const float* __restrict__ dbih1, const float* __restrict__ dbhh1,
    const float* __restrict__ fcW, const float* __restrict__ Qw,
    const float* __restrict__ Kw,  const float* __restrict__ Vw,
    f16* __restrict__ W0, f16* __restrict__ W1, f16* __restrict__ WD0A,
    f16* __restrict__ WD0B, f16* __restrict__ WD1, f16* __restrict__ FCp,
    f16* __restrict__ QKVW, float* __restrict__ B0, float* __restrict__ B1,
    float* __restrict__ BD0, float* __restrict__ BD1)
{
    const int sec = blockIdx.y;
    const int idx0 = blockIdx.x * blockDim.x + threadIdx.x;
    const int stride = gridDim.x * blockDim.x;
    switch (sec) {
    case 0: for (int i = idx0; i < 512*192; i += stride) {
                int g = i / 192, c = i % 192;
                W0[i] = (f16)(c < 64 ? Wih0[g*64 + c] : Whh0[g*128 + (c-64)]);
            } break;
    case 1: for (int i = idx0; i < 512*256; i += stride) {
                int g = i >> 8, c = i & 255;
                W1[i] = (f16)(c < 128 ? Wih1[g*128 + c] : Whh1[g*128 + (c-128)]);
            } break;
    case 2: for (int i = idx0; i < 512*64; i += stride) WD0A[i] = (f16)dWih0[i]; break;
    case 3: for (int i = idx0; i < 512*128; i += stride) WD0B[i] = (f16)dWhh0[i]; break;
    case 4: for (int i = idx0; i < 512*256; i += stride) {
                int g = i >> 8, c = i & 255;
                WD1[i] = (f16)(c < 128 ? dWih1[g*128 + c] : dWhh1[g*128 + (c-128)]);
            } break;
    case 5: for (int i = idx0; i < 64*128; i += stride) FCp[i] = (f16)fcW[i]; break;
    case 6: for (int i = idx0; i < 3*128*128; i += stride) {
                int m = i >> 14, r = i & 16383;
                const float* src = (m == 0) ? Qw : ((m == 1) ? Kw : Vw);
                QKVW[i] = (f16)src[r];
            } break;
    case 7: for (int i = idx0; i < 2048; i += stride) {
                int w = i >> 9, g = i & 511;
                if      (w == 0) B0[g]  = bih0[g]  + bhh0[g];
                else if (w == 1) B1[g]  = bih1[g]  + bhh1[g];
                else if (w == 2) BD0[g] = dbih0[g] + dbhh0[g];
                else             BD1[g] = dbih1[g] + dbhh1[g];
            } break;
    }
}

// ---------------- K1/K2: encoder LSTM layer, persistent, 2 batch rows/block ----------------
// 256 blocks x 512 threads. Thread j owns gate column j (weights in VGPRs, fp16x2).
template<int KIN, bool FIRST>
__global__ __launch_bounds__(512, 2) void enc_layer(
    const f16* __restrict__ Wpack, const float* __restrict__ bias,
    const float* __restrict__ xf32, const f16* __restrict__ xf16,
    f16* __restrict__ yout, float* __restrict__ hfin, float* __restrict__ cfin)
{
    constexpr int KP = KIN + nH;       // halfs per weight row
    constexpr int NP = KP / 2;         // u32 per row
    const int j  = threadIdx.x;
    const int b0 = blockIdx.x * 2;
    u32 wreg[NP];
    {
        const uint4* wg = (const uint4*)(Wpack + (size_t)j * KP);
        #pragma unroll
        for (int i = 0; i < NP/4; i++) {
            uint4 w = wg[i];
            wreg[4*i+0] = w.x; wreg[4*i+1] = w.y; wreg[4*i+2] = w.z; wreg[4*i+3] = w.w;
        }
    }
    const float bj = bias[j];
    const int gtype = j >> 7;          // 0:i 1:f 2:g 3:o

    __shared__ __align__(16) u32 xs[2][KIN/2];
    __shared__ __align__(16) u32 hs[2][nH/2];
    __shared__ float cs[2][nH];
    __shared__ float gact[2][nG];

    if (j < 256) { ((f16*)hs)[j] = (f16)0.f; ((float*)cs)[j] = 0.f; }
    __syncthreads();

    for (int t = 0; t < nS; t++) {
        // stage input (2 rows)
        if (j < 128) {
            if constexpr (FIRST) {           // x: [B][S][D] fp32 -> fp16
                const int r = j >> 6, d = j & 63;
                ((f16*)xs)[j] = (f16)xf32[(size_t)(b0+r)*(nS*nD) + (size_t)t*nD + d];
            } else {                         // y0: [S][B][H] fp16, u32 pair loads
                const int r = j >> 6, c = j & 63;
                ((u32*)xs)[j] = ((const u32*)(xf16 + (size_t)t*(nB*nH) + (size_t)(b0+r)*nH))[c];
            }
        }
        __syncthreads();

        float ax0 = bj, ax1 = bj, ah0 = 0.f, ah1 = 0.f;
        #pragma unroll
        for (int p = 0; p < KIN/8; p++) {
            uint4 x0 = ((const uint4*)xs[0])[p], x1 = ((const uint4*)xs[1])[p];
            ax0 = fdot2u(wreg[4*p+0], x0.x, ax0); ax0 = fdot2u(wreg[4*p+1], x0.y, ax0);
            ax0 = fdot2u(wreg[4*p+2], x0.z, ax0); ax0 = fdot2u(wreg[4*p+3], x0.w, ax0);
            ax1 = fdot2u(wreg[4*p+0], x1.x, ax1); ax1 = fdot2u(wreg[4*p+1], x1.y, ax1);
            ax1 = fdot2u(wreg[4*p+2], x1.z, ax1); ax1 = fdot2u(wreg[4*p+3], x1.w, ax1);
        }
        #pragma unroll
        for (int p = 0; p < nH/8; p++) {
            uint4 h0 = ((const uint4*)hs[0])[p], h1 = ((const uint4*)hs[1])[p];
            ah0 = fdot2u(wreg[KIN/2+4*p+0], h0.x, ah0); ah0 = fdot2u(wreg[KIN/2+4*p+1], h0.y, ah0);
            ah0 = fdot2u(wreg[KIN/2+4*p+2], h0.z, ah0); ah0 = fdot2u(wreg[KIN/2+4*p+3], h0.w, ah0);
            ah1 = fdot2u(wreg[KIN/2+4*p+0], h1.x, ah1); ah1 = fdot2u(wreg[KIN/2+4*p+1], h1.y, ah1);
            ah1 = fdot2u(wreg[KIN/2+4*p+2], h1.z, ah1); ah1 = fdot2u(wreg[KIN/2+4*p+3], h1.w, ah1);
        }
        {
            const float a0 = ax0 + ah0, a1 = ax1 + ah1;
            float v0, v1;
            if (gtype == 2) { v0 = tanh_f(a0); v1 = tanh_f(a1); }
            else            { v0 = sigm_f(a0); v1 = sigm_f(a1); }
            gact[0][j] = v0; gact[1][j] = v1;
        }
        __syncthreads();
        if (j < 256) {
            const int r = j >> 7, kk = j & 127;
            const float gi = gact[r][kk], gf = gact[r][128+kk];
            const float gg = gact[r][256+kk], go = gact[r][384+kk];
            const float c2 = gf * cs[r][kk] + gi * gg;
            const float h2 = go * tanh_f(c2);
            cs[r][kk] = c2;
            ((f16*)hs)[r*nH + kk] = (f16)h2;
            yout[(size_t)t*(nB*nH) + (size_t)(b0+r)*nH + kk] = (f16)h2;
            if (t == nS-1) { hfin[(b0+r)*nH + kk] = h2; cfin[(b0+r)*nH + kk] = c2; }
        }
        __syncthreads();
    }
}

// ---------------- K3: q,k,v = y1 @ {Qw,Kw,Vw}^T ----------------
// grid (512 b, 8 s-tiles) x 384 thr; thread = (m in {q,k,v}, out column hp)
__global__ __launch_bounds__(384) void qkv_kernel(
    const f16* __restrict__ y1, const f16* __restrict__ W,
    f16* __restrict__ qo, f16* __restrict__ ko, f16* __restrict__ vo)
{
    const int b = blockIdx.x, tile = blockIdx.y, j = threadIdx.x;
    const int m = j >> 7, hp = j & 127;
    u32 wreg[64];
    {
        const uint4* wg = (const uint4*)(W + ((size_t)(m*128 + hp)) * nH);
        #pragma unroll
        for (int i = 0; i < 16; i++) {
            uint4 w = wg[i];
            wreg[4*i+0] = w.x; wreg[4*i+1] = w.y; wreg[4*i+2] = w.z; wreg[4*i+3] = w.w;
        }
    }
    __shared__ __align__(16) u32 ys[32][64];
    for (int i = j; i < 32*64; i += 384) {
        const int sr = i >> 6, c = i & 63;
        ys[sr][c] = ((const u32*)(y1 + (size_t)(tile*32 + sr)*(nB*nH) + (size_t)b*nH))[c];
    }
    __syncthreads();
    f16* outp = (m == 0) ? qo : ((m == 1) ? ko : vo);
    for (int sl = 0; sl < 32; sl++) {
        float a0 = 0.f, a1 = 0.f;
        #pragma unroll
        for (int p = 0; p < 16; p++) {
            uint4 ya = ((const uint4*)ys[sl])[p];
            a0 = fdot2u(wreg[4*p+0], ya.x, a0); a1 = fdot2u(wreg[4*p+1], ya.y, a1);
            a0 = fdot2u(wreg[4*p+2], ya.z, a0); a1 = fdot2u(wreg[4*p+3], ya.w, a1);
        }
        outp[(size_t)b*(nS*nH) + (size_t)(tile*32 + sl)*nH + hp] = (f16)(a0 + a1);
    }
}

// ---------------- K4: attention core, 1 block per batch row ----------------
// scores -> softmax -> P@V -> proj(Pw) fused; writes hinit = h_final + proj
__global__ __launch_bounds__(256) void attn_kernel(
    const f16* __restrict__ q, const f16* __restrict__ k, const f16* __restrict__ v,
    const float* __restrict__ Pw, const float* __restrict__ hf0,
    const float* __restrict__ hf1, float* __restrict__ hinit)
{
    const int b = blockIdx.x, j = threadIdx.x;
    __shared__ u32 ks[256*65];     // k rows, odd-word stride padding
    __shared__ u32 vTs[128*129];   // v transposed [h][s-pairs], padded
    __shared__ __align__(16) u32 qrow[64];
    __shared__ u32 p16[128];       // softmax weights fp16-packed
    __shared__ float red[8];
    __shared__ float pw_s[2][256];
    __shared__ float pvpart[2][128];

    const size_t bb = (size_t)b * (nS*nH);
    {
        const u32* src = (const u32*)(k + bb);
        for (int i = j; i < 256*64; i += 256) ks[(i>>6)*65 + (i&63)] = src[i];
    }
    {
        const u32* src = (const u32*)(v + bb);
        f16* vt = (f16*)vTs;
        for (int i = j; i < 256*64; i += 256) {
            const int s = i >> 6, c = i & 63;
            const f16x2 w = __builtin_bit_cast(f16x2, src[i]);
            vt[(2*c)  *258 + s] = w.x;
            vt[(2*c+1)*258 + s] = w.y;
        }
    }
    for (int i = j; i < 512; i += 256) ((float*)pw_s)[i] = Pw[i];
    float pj0 = 0.f, pj1 = 0.f;
    __syncthreads();

    const int lane = j & 63, wid = j >> 6;
    for (int s = 0; s < nS; s++) {
        if (j < 64) qrow[j] = ((const u32*)(q + bb + (size_t)s*nH))[j];
        __syncthreads();
        // score for key row t=j
        float s0 = 0.f, s1 = 0.f;
        #pragma unroll
        for (int p = 0; p < 16; p++) {
            uint4 qa = ((const uint4*)qrow)[p];
            s0 = fdot2u(ks[j*65 + 4*p+0], qa.x, s0);
            s1 = fdot2u(ks[j*65 + 4*p+1], qa.y, s1);
            s0 = fdot2u(ks[j*65 + 4*p+2], qa.z, s0);
            s1 = fdot2u(ks[j*65 + 4*p+3], qa.w, s1);
        }
        const float sc = s0 + s1;
        float mx = sc;
        #pragma unroll
        for (int msk = 32; msk; msk >>= 1) mx = fmaxf(mx, __shfl_xor(mx, msk));
        if (lane == 0) red[wid] = mx;
        __syncthreads();
        mx = fmaxf(fmaxf(red[0], red[1]), fmaxf(red[2], red[3]));
        const float e = __expf(sc - mx);
        float sm = e;
        #pragma unroll
        for (int msk = 32; msk; msk >>= 1) sm += __shfl_xor(sm, msk);
        if (lane == 0) red[4+wid] = sm;
        __syncthreads();
        sm = (red[4] + red[5]) + (red[6] + red[7]);
        ((f16*)p16)[j] = (f16)(e * __builtin_amdgcn_rcpf(sm));
        __syncthreads();
        // P @ V : thread (h, t-half)
        {
            const int h = j & 127, tb = (j >> 7) * 64;
            float a0 = 0.f, a1 = 0.f;
            #pragma unroll
            for (int p = 0; p < 64; p += 2) {
                a0 = fdot2u(vTs[h*129 + tb + p],     p16[tb + p],     a0);
                a1 = fdot2u(vTs[h*129 + tb + p + 1], p16[tb + p + 1], a1);
            }
            pvpart[j >> 7][h] = a0 + a1;
        }
        __syncthreads();
        if (j < 128) {
            const float ao = pvpart[0][j] + pvpart[1][j];
            pj0 += pw_s[0][s] * ao;
            pj1 += pw_s[1][s] * ao;
        }
    }
    if (j < 128) {
        hinit[(size_t)b*nH + j]                      = hf0[b*nH + j] + pj0;
        hinit[(size_t)(nB*nH) + (size_t)b*nH + j]    = hf1[b*nH + j] + pj1;
    }
}

// ---------------- K5: autoregressive decoder, persistent, 2 rows/block ----------------
__global__ __launch_bounds__(512, 2) void dec_kernel(
    const f16* __restrict__ WD0A, const f16* __restrict__ WD0B,
    const f16* __restrict__ WD1,  const f16* __restrict__ FCp,
    const float* __restrict__ BD0, const float* __restrict__ BD1,
    const float* __restrict__ fcb,
    const float* __restrict__ hinit, const float* __restrict__ cf0,
    const float* __restrict__ cf1, float* __restrict__ out)
{
    const int j = threadIdx.x, b0 = blockIdx.x * 2;
    u32 whh0[64], w1[128];
    {
        const uint4* wg = (const uint4*)(WD0B + (size_t)j * 128);
        #pragma unroll
        for (int i = 0; i < 16; i++) {
            uint4 w = wg[i];
            whh0[4*i+0] = w.x; whh0[4*i+1] = w.y; whh0[4*i+2] = w.z; whh0[4*i+3] = w.w;
        }
    }
    {
        const uint4* wg = (const uint4*)(WD1 + (size_t)j * 256);
        #pragma unroll
        for (int i = 0; i < 32; i++) {
            uint4 w = wg[i];
            w1[4*i+0] = w.x; w1[4*i+1] = w.y; w1[4*i+2] = w.z; w1[4*i+3] = w.w;
        }
    }
    const float bd0j = BD0[j], bd1j = BD1[j];
    const int gtype = j >> 7;

    __shared__ u32 wih0s[512*33];   // dec Wih0, padded row stride 33 words
    __shared__ u32 fcs[64*65];      // fc_W, padded row stride 65 words
    __shared__ __align__(16) u32 h0s[2][64], h1s[2][64];
    __shared__ __align__(16) u32 pr16[2][32];
    __shared__ float c0s[2][128], c1s[2][128];
    __shared__ float gact[2][512];

    {
        const u32* src = (const u32*)WD0A;
        for (int i = j; i < 512*32; i += 512) wih0s[(i>>5)*33 + (i&31)] = src[i];
    }
    {
        const u32* src = (const u32*)FCp;
        for (int i = j; i < 64*64; i += 512) fcs[(i>>6)*65 + (i&63)] = src[i];
    }
    if (j < 256) {
        const int r = j >> 7, kk = j & 127;
        c0s[r][kk] = cf0[(b0+r)*nH + kk];
        c1s[r][kk] = cf1[(b0+r)*nH + kk];
        ((f16*)h0s)[r*nH + kk] = (f16)hinit[(size_t)(b0+r)*nH + kk];
        ((f16*)h1s)[r*nH + kk] = (f16)hinit[(size_t)(nB*nH) + (size_t)(b0+r)*nH + kk];
    }
    if (j < 128) ((f16*)pr16)[j] = (f16)0.f;
    __syncthreads();

    for (int t = 0; t < nS; t++) {
        // ---- layer 0 gates ----
        float ax0 = bd0j, ax1 = bd0j, ah0 = 0.f, ah1 = 0.f;
        #pragma unroll
        for (int p = 0; p < 32; p++) {
            const u32 wa = wih0s[j*33 + p];
            ax0 = fdot2u(wa, pr16[0][p], ax0);
            ax1 = fdot2u(wa, pr16[1][p], ax1);
        }
        #pragma unroll
        for (int p = 0; p < 16; p++) {
            uint4 ha = ((const uint4*)h0s[0])[p], hb = ((const uint4*)h0s[1])[p];
            ah0 = fdot2u(whh0[4*p+0], ha.x, ah0); ah0 = fdot2u(whh0[4*p+1], ha.y, ah0);
            ah0 = fdot2u(whh0[4*p+2], ha.z, ah0); ah0 = fdot2u(whh0[4*p+3], ha.w, ah0);
            ah1 = fdot2u(whh0[4*p+0], hb.x, ah1); ah1 = fdot2u(whh0[4*p+1], hb.y, ah1);
            ah1 = fdot2u(whh0[4*p+2], hb.z, ah1); ah1 = fdot2u(whh0[4*p+3], hb.w, ah1);
        }
        {
            const float a0 = ax0 + ah0, a1 = ax1 + ah1;
            float v0, v1;
            if (gtype == 2) { v0 = tanh_f(a0); v1 = tanh_f(a1); }
            else            { v0 = sigm_f(a0); v1 = sigm_f(a1); }
            gact[0][j] = v0; gact[1][j] = v1;
        }
        __syncthreads();
        if (j < 256) {
            const int r = j >> 7, kk = j & 127;
            const float c2 = gact[r][128+kk] * c0s[r][kk] + gact[r][kk] * gact[r][256+kk];
            c0s[r][kk] = c2;
            ((f16*)h0s)[r*nH + kk] = (f16)(gact[r][384+kk] * tanh_f(c2));
        }
        __syncthreads();
        // ---- layer 1 gates ----
        float ux0 = bd1j, ux1 = bd1j, uh0 = 0.f, uh1 = 0.f;
        #pragma unroll
        for (int p = 0; p < 16; p++) {
            uint4 ha = ((const uint4*)h0s[0])[p], hb = ((const uint4*)h0s[1])[p];
            ux0 = fdot2u(w1[4*p+0], ha.x, ux0); ux0 = fdot2u(w1[4*p+1], ha.y, ux0);
            ux0 = fdot2u(w1[4*p+2], ha.z, ux0); ux0 = fdot2u(w1[4*p+3], ha.w, ux0);
            ux1 = fdot2u(w1[4*p+0], hb.x, ux1); ux1 = fdot2u(w1[4*p+1], hb.y, ux1);
            ux1 = fdot2u(w1[4*p+2], hb.z, ux1); ux1 = fdot2u(w1[4*p+3], hb.w, ux1);
        }
        #pragma unroll
        for (int p = 0; p < 16; p++) {
            uint4 ha = ((const uint4*)h1s[0])[p], hb = ((const uint4*)h1s[1])[p];
            uh0 = fdot2u(w1[64+4*p+0], ha.x, uh0); uh0 = fdot2u(w1[64+4*p+1], ha.y, uh0);
            uh0 = fdot2u(w1[64+4*p+2], ha.z, uh0); uh0 = fdot2u(w1[64+4*p+3], ha.w, uh0);
            uh1 = fdot2u(w1[64+4*p+0], hb.x, uh1); uh1 = fdot2u(w1[64+4*p+1], hb.y, uh1);
            uh1 = fdot2u(w1[64+4*p+2], hb.z, uh1); uh1 = fdot2u(w1[64+4*p+3], hb.w, uh1);
        }
        {
            const float a0 = ux0 + uh0, a1 = ux1 + uh1;
            float v0, v1;
            if (gtype == 2) { v0 = tanh_f(a0); v1 = tanh_f(a1); }
            else            { v0 = sigm_f(a0); v1 = sigm_f(a1); }
            gact[0][j] = v0; gact[1][j] = v1;
        }
        __syncthreads();
        if (j < 256) {
            const int r = j >> 7, kk = j & 127;
            const float c2 = gact[r][128+kk] * c1s[r][kk] + gact[r][kk] * gact[r][256+kk];
            c1s[r][kk] = c2;
            ((f16*)h1s)[r*nH + kk] = (f16)(gact[r][384+kk] * tanh_f(c2));
        }
        __syncthreads();
        // ---- fc + feedback ----
        if (j < 128) {
            const int r = j >> 6, d = j & 63;
            float a0 = fcb[d], a1 = 0.f;
            #pragma unroll
            for (int p = 0; p < 64; p += 2) {
                a0 = fdot2u(fcs[d*65 + p],     h1s[r][p],     a0);
                a1 = fdot2u(fcs[d*65 + p + 1], h1s[r][p + 1], a1);
            }
            const float pred = a0 + a1;
            out[(size_t)(b0+r)*(nS*nD) + (size_t)t*nD + d] = pred;
            ((f16*)pr16)[r*64 + d] = (f16)pred;
        }
        __syncthreads();
    }
}

// ---------------- launch ----------------
extern "C" void kernel_launch(void* const* d_in, const int* in_sizes, int n_in,
                              void* d_out, int out_size, void* d_ws, size_t ws_size,
                              hipStream_t stream)
{
    (void)in_sizes; (void)n_in; (void)out_size;
    if (ws_size < WS_NEED) return;   // workspace too small — cannot proceed

    const float* x      = (const float*)d_in[0];
    const float* eWih0  = (const float*)d_in[1];
    const float* eWhh0  = (const float*)d_in[2];
    const float* ebih0  = (const float*)d_in[3];
    const float* ebhh0  = (const float*)d_in[4];
    const float* eWih1  = (const float*)d_in[5];
    const float* eWhh1  = (const float*)d_in[6];
    const float* ebih1  = (const float*)d_in[7];
    const float* ebhh1  = (const float*)d_in[8];
    const float* dWih0  = (const float*)d_in[9];
    const float* dWhh0  = (const float*)d_in[10];
    const float* dbih0  = (const float*)d_in[11];
    const float* dbhh0  = (const float*)d_in[12];
    const float* dWih1  = (const float*)d_in[13];
    const float* dWhh1  = (const float*)d_in[14];
    const float* dbih1  = (const float*)d_in[15];
    const float* dbhh1  = (const float*)d_in[16];
    const float* fcW    = (const float*)d_in[17];
    const float* fcb    = (const float*)d_in[18];
    const float* Qw     = (const float*)d_in[19];
    const float* Kw     = (const float*)d_in[20];
    const float* Vw     = (const float*)d_in[21];
    const float* Pw     = (const float*)d_in[22];

    char* ws = (char*)d_ws;
    f16*   W0    = (f16*)(ws + OFF_W0);
    f16*   W1    = (f16*)(ws + OFF_W1);
    f16*   WD0A  = (f16*)(ws + OFF_WD0A);
    f16*   WD0B  = (f16*)(ws + OFF_WD0B);
    f16*   WD1   = (f16*)(ws + OFF_WD1);
    f16*   FCp   = (f16*)(ws + OFF_FC);
    f16*   QKVW  = (f16*)(ws + OFF_QKVW);
    float* B0f   = (float*)(ws + OFF_B0);
    float* B1f   = (float*)(ws + OFF_B1);
    float* BD0f  = (float*)(ws + OFF_BD0);
    float* BD1f  = (float*)(ws + OFF_BD1);
    float* HF0   = (float*)(ws + OFF_HF0);
    float* CF0   = (float*)(ws + OFF_CF0);
    float* HF1   = (float*)(ws + OFF_HF1);
    float* CF1   = (float*)(ws + OFF_CF1);
    float* HINIT = (float*)(ws + OFF_HINIT);
    f16*   Y0    = (f16*)(ws + OFF_Y0);
    f16*   Y1    = (f16*)(ws + OFF_Y1);
    f16*   Qb    = (f16*)(ws + OFF_Q);
    f16*   Kb    = (f16*)(ws + OFF_K);
    f16*   Vb    = (f16*)(ws + OFF_V);

    prep_kernel<<<dim3(64, 8), 256, 0, stream>>>(
        eWih0, eWhh0, ebih0, ebhh0, eWih1, eWhh1, ebih1, ebhh1,
        dWih0, dWhh0, dbih0, dbhh0, dWih1, dWhh1, dbih1, dbhh1,
        fcW, Qw, Kw, Vw,
        W0, W1, WD0A, WD0B, WD1, FCp, QKVW, B0f, B1f, BD0f, BD1f);

    enc_layer<64, true><<<256, 512, 0, stream>>>(W0, B0f, x, nullptr, Y0, HF0, CF0);
    enc_layer<128, false><<<256, 512, 0, stream>>>(W1, B1f, nullptr, Y0, Y1, HF1, CF1);
    qkv_kernel<<<dim3(512, 8), 384, 0, stream>>>(Y1, QKVW, Qb, Kb, Vb);
    attn_kernel<<<512, 256, 0, stream>>>(Qb, Kb, Vb, Pw, HF0, HF1, HINIT);
    dec_kernel<<<256, 512, 0, stream>>>(WD0A, WD0B, WD1, FCp, BD0f, BD1f, fcb,
                                        HINIT, CF0, CF1, (float*)d_out);
}

// Round 6
// 5030.490 us; speedup vs baseline: 1.0006x; 1.0006x over previous
//
#include <hip/hip_runtime.h>
#include <cstdint>
#include <cstddef>

typedef unsigned int u32;
typedef _Float16 f16;
typedef f16 f16x2 __attribute__((ext_vector_type(2)));

constexpr int nB = 512, nS = 256, nD = 64, nH = 128, nG = 512;

// ---------------- workspace layout (bytes) ----------------
constexpr size_t OFF_W0   = 0;                                   // [512][192] f16 enc0 Wih|Whh
constexpr size_t OFF_W1   = OFF_W0   + (size_t)512*192*2;        // [512][256] f16 enc1 Wih|Whh
constexpr size_t OFF_WD0A = OFF_W1   + (size_t)512*256*2;        // [512][64]  f16 dec Wih0
constexpr size_t OFF_WD0B = OFF_WD0A + (size_t)512*64*2;         // [512][128] f16 dec Whh0
constexpr size_t OFF_WD1  = OFF_WD0B + (size_t)512*128*2;        // [512][256] f16 dec Wih1|Whh1
constexpr size_t OFF_FC   = OFF_WD1  + (size_t)512*256*2;        // [64][128]  f16 fc_W
constexpr size_t OFF_QKVW = OFF_FC   + (size_t)64*128*2;         // [3][128][128] f16 Qw,Kw,Vw
constexpr size_t OFF_B0   = OFF_QKVW + (size_t)3*128*128*2;      // [512] f32 (bih+bhh)
constexpr size_t OFF_B1   = OFF_B0   + 512*4;
constexpr size_t OFF_BD0  = OFF_B1   + 512*4;
constexpr size_t OFF_BD1  = OFF_BD0  + 512*4;
constexpr size_t OFF_HF0  = OFF_BD1  + 512*4;                    // [B][H] f32 enc L0 final h
constexpr size_t OFF_CF0  = OFF_HF0  + (size_t)nB*nH*4;
constexpr size_t OFF_HF1  = OFF_CF0  + (size_t)nB*nH*4;
constexpr size_t OFF_CF1  = OFF_HF1  + (size_t)nB*nH*4;
constexpr size_t OFF_HINIT= OFF_CF1  + (size_t)nB*nH*4;          // [2][B][H] f32 (hfin + proj)
constexpr size_t OFF_Y0   = OFF_HINIT+ (size_t)2*nB*nH*4;        // [S][B][H] f16
constexpr size_t OFF_Y1   = OFF_Y0   + (size_t)nS*nB*nH*2;       // [S][B][H] f16
constexpr size_t OFF_Q    = OFF_Y1   + (size_t)nS*nB*nH*2;       // [B][S][H] f16
constexpr size_t OFF_K    = OFF_Q    + (size_t)nB*nS*nH*2;
constexpr size_t OFF_V    = OFF_K    + (size_t)nB*nS*nH*2;
constexpr size_t WS_NEED  = OFF_V    + (size_t)nB*nS*nH*2;       // ~170 MB

// ---------------- helpers ----------------
__device__ __forceinline__ float fdot2u(u32 w, u32 x, float acc) {
#if defined(__has_builtin)
#if __has_builtin(__builtin_amdgcn_fdot2)
    return __builtin_amdgcn_fdot2(__builtin_bit_cast(f16x2, w),
                                  __builtin_bit_cast(f16x2, x), acc, false);
#else
    const f16x2 a = __builtin_bit_cast(f16x2, w), b = __builtin_bit_cast(f16x2, x);
    return acc + (float)a.x * (float)b.x + (float)a.y * (float)b.y;
#endif
#else
    const f16x2 a = __builtin_bit_cast(f16x2, w), b = __builtin_bit_cast(f16x2, x);
    return acc + (float)a.x * (float)b.x + (float)a.y * (float)b.y;
#endif
}

__device__ __forceinline__ float sigm_f(float x) {
    return __builtin_amdgcn_rcpf(1.0f + __expf(-x));
}
__device__ __forceinline__ float tanh_f(float x) {
    // 1 - 2/(e^{2x}+1); exp overflow/underflow saturate correctly to +-1
    return 1.0f - 2.0f * __builtin_amdgcn_rcpf(__expf(2.0f * x) + 1.0f);
}

// ---------------- K0: weight pack/convert (fp32 -> fp16, bias fuse) ----------------
__global__ void prep_kernel(
    const float* __restrict__ Wih0, const float* __restrict__ Whh0,
    const float* __restrict__ bih0, const float* __restrict__ bhh0,
    const float* __restrict__ Wih1, const float* __restrict__ Whh1,
    const float* __restrict__ bih1, const float* __restrict__ bhh1,
    const float* __restrict__ dWih0, const float* __restrict__ dWhh0,
    const float* __restrict__ dbih0, const float* __restrict__ dbhh0,
    const float* __restrict__ dWih1, const float* __restrict__ dWhh1,
    const float* __restrict__ dbih1, const float* __restrict__ dbhh1,
    const float* __restrict__ fcW, const float* __restrict__ Qw,
    const float* __restrict__ Kw,  const float* __restrict__ Vw,
    f16* __restrict__ W0, f16* __restrict__ W1, f16* __restrict__ WD0A,
    f16* __restrict__ WD0B, f16* __restrict__ WD1, f16* __restrict__ FCp,
    f16* __restrict__ QKVW, float* __restrict__ B0, float* __restrict__ B1,
    float* __restrict__ BD0, float* __restrict__ BD1)
{
    const int sec = blockIdx.y;
    const int idx0 = blockIdx.x * blockDim.x + threadIdx.x;
    const int stride = gridDim.x * blockDim.x;
    switch (sec) {
    case 0: for (int i = idx0; i < 512*192; i += stride) {
                int g = i / 192, c = i % 192;
                W0[i] = (f16)(c < 64 ? Wih0[g*64 + c] : Whh0[g*128 + (c-64)]);
            } break;
    case 1: for (int i = idx0; i < 512*256; i += stride) {
                int g = i >> 8, c = i & 255;
                W1[i] = (f16)(c < 128 ? Wih1[g*128 + c] : Whh1[g*128 + (c-128)]);
            } break;
    case 2: for (int i = idx0; i < 512*64; i += stride) WD0A[i] = (f16)dWih0[i]; break;
    case 3: for (int i = idx0; i < 512*128; i += stride) WD0B[i] = (f16)dWhh0[i]; break;
    case 4: for (int i = idx0; i < 512*256; i += stride) {
                int g = i >> 8, c = i & 255;
                WD1[i] = (f16)(c < 128 ? dWih1[g*128 + c] : dWhh1[g*128 + (c-128)]);
            } break;
    case 5: for (int i = idx0; i < 64*128; i += stride) FCp[i] = (f16)fcW[i]; break;
    case 6: for (int i = idx0; i < 3*128*128; i += stride) {
                int m = i >> 14, r = i & 16383;
                const float* src = (m == 0) ? Qw : ((m == 1) ? Kw : Vw);
                QKVW[i] = (f16)src[r];
            } break;
    case 7: for (int i = idx0; i < 2048; i += stride) {
                int w = i >> 9, g = i & 511;
                if      (w == 0) B0[g]  = bih0[g]  + bhh0[g];
                else if (w == 1) B1[g]  = bih1[g]  + bhh1[g];
                else if (w == 2) BD0[g] = dbih0[g] + dbhh0[g];
                else             BD1[g] = dbih1[g] + dbhh1[g];
            } break;
    }
}

// ---------------- K1/K2: encoder LSTM layer, persistent, 2 batch rows/block ----------------
// 256 blocks x 512 threads. Thread j owns gate column j (weights in VGPRs, fp16x2).
// __launch_bounds__(512, 1): grid==256 blocks on 256 CUs => only 1 block/CU ever
// resident; ",1" lets the compiler use up to 256 VGPRs (8-wave block still fits
// the 2048-reg/CU pool). (512,2) capped at 128 VGPRs -> 2.2 GB scratch spill/dispatch.
template<int KIN, bool FIRST>
__global__ __launch_bounds__(512, 1) void enc_layer(
    const f16* __restrict__ Wpack, const float* __restrict__ bias,
    const float* __restrict__ xf32, const f16* __restrict__ xf16,
    f16* __restrict__ yout, float* __restrict__ hfin, float* __restrict__ cfin)
{
    constexpr int KP = KIN + nH;       // halfs per weight row
    constexpr int NP = KP / 2;         // u32 per row
    const int j  = threadIdx.x;
    const int b0 = blockIdx.x * 2;
    u32 wreg[NP];
    {
        const uint4* wg = (const uint4*)(Wpack + (size_t)j * KP);
        #pragma unroll
        for (int i = 0; i < NP/4; i++) {
            uint4 w = wg[i];
            wreg[4*i+0] = w.x; wreg[4*i+1] = w.y; wreg[4*i+2] = w.z; wreg[4*i+3] = w.w;
        }
    }
    const float bj = bias[j];
    const int gtype = j >> 7;          // 0:i 1:f 2:g 3:o

    __shared__ __align__(16) u32 xs[2][KIN/2];
    __shared__ __align__(16) u32 hs[2][nH/2];
    __shared__ float cs[2][nH];
    __shared__ float gact[2][nG];

    if (j < 256) { ((f16*)hs)[j] = (f16)0.f; ((float*)cs)[j] = 0.f; }
    __syncthreads();

    for (int t = 0; t < nS; t++) {
        // stage input (2 rows)
        if (j < 128) {
            if constexpr (FIRST) {           // x: [B][S][D] fp32 -> fp16
                const int r = j >> 6, d = j & 63;
                ((f16*)xs)[j] = (f16)xf32[(size_t)(b0+r)*(nS*nD) + (size_t)t*nD + d];
            } else {                         // y0: [S][B][H] fp16, u32 pair loads
                const int r = j >> 6, c = j & 63;
                ((u32*)xs)[j] = ((const u32*)(xf16 + (size_t)t*(nB*nH) + (size_t)(b0+r)*nH))[c];
            }
        }
        __syncthreads();

        float ax0 = bj, ax1 = bj, ah0 = 0.f, ah1 = 0.f;
        #pragma unroll
        for (int p = 0; p < KIN/8; p++) {
            uint4 x0 = ((const uint4*)xs[0])[p], x1 = ((const uint4*)xs[1])[p];
            ax0 = fdot2u(wreg[4*p+0], x0.x, ax0); ax0 = fdot2u(wreg[4*p+1], x0.y, ax0);
            ax0 = fdot2u(wreg[4*p+2], x0.z, ax0); ax0 = fdot2u(wreg[4*p+3], x0.w, ax0);
            ax1 = fdot2u(wreg[4*p+0], x1.x, ax1); ax1 = fdot2u(wreg[4*p+1], x1.y, ax1);
            ax1 = fdot2u(wreg[4*p+2], x1.z, ax1); ax1 = fdot2u(wreg[4*p+3], x1.w, ax1);
        }
        #pragma unroll
        for (int p = 0; p < nH/8; p++) {
            uint4 h0 = ((const uint4*)hs[0])[p], h1 = ((const uint4*)hs[1])[p];
            ah0 = fdot2u(wreg[KIN/2+4*p+0], h0.x, ah0); ah0 = fdot2u(wreg[KIN/2+4*p+1], h0.y, ah0);
            ah0 = fdot2u(wreg[KIN/2+4*p+2], h0.z, ah0); ah0 = fdot2u(wreg[KIN/2+4*p+3], h0.w, ah0);
            ah1 = fdot2u(wreg[KIN/2+4*p+0], h1.x, ah1); ah1 = fdot2u(wreg[KIN/2+4*p+1], h1.y, ah1);
            ah1 = fdot2u(wreg[KIN/2+4*p+2], h1.z, ah1); ah1 = fdot2u(wreg[KIN/2+4*p+3], h1.w, ah1);
        }
        {
            const float a0 = ax0 + ah0, a1 = ax1 + ah1;
            float v0, v1;
            if (gtype == 2) { v0 = tanh_f(a0); v1 = tanh_f(a1); }
            else            { v0 = sigm_f(a0); v1 = sigm_f(a1); }
            gact[0][j] = v0; gact[1][j] = v1;
        }
        __syncthreads();
        if (j < 256) {
            const int r = j >> 7, kk = j & 127;
            const float gi = gact[r][kk], gf = gact[r][128+kk];
            const float gg = gact[r][256+kk], go = gact[r][384+kk];
            const float c2 = gf * cs[r][kk] + gi * gg;
            const float h2 = go * tanh_f(c2);
            cs[r][kk] = c2;
            ((f16*)hs)[r*nH + kk] = (f16)h2;
            yout[(size_t)t*(nB*nH) + (size_t)(b0+r)*nH + kk] = (f16)h2;
            if (t == nS-1) { hfin[(b0+r)*nH + kk] = h2; cfin[(b0+r)*nH + kk] = c2; }
        }
        __syncthreads();
    }
}

// ---------------- K3: q,k,v = y1 @ {Qw,Kw,Vw}^T ----------------
// grid (512 b, 8 s-tiles) x 384 thr; thread = (m in {q,k,v}, out column hp)
// (384,1): 6-wave block, cap 256 VGPRs (wreg[64]+temps ~ 100 fits without spill;
// default bounds assume 1024-thread blocks -> 128-VGPR cap -> would spill).
__global__ __launch_bounds__(384, 1) void qkv_kernel(
    const f16* __restrict__ y1, const f16* __restrict__ W,
    f16* __restrict__ qo, f16* __restrict__ ko, f16* __restrict__ vo)
{
    const int b = blockIdx.x, tile = blockIdx.y, j = threadIdx.x;
    const int m = j >> 7, hp = j & 127;
    u32 wreg[64];
    {
        const uint4* wg = (const uint4*)(W + ((size_t)(m*128 + hp)) * nH);
        #pragma unroll
        for (int i = 0; i < 16; i++) {
            uint4 w = wg[i];
            wreg[4*i+0] = w.x; wreg[4*i+1] = w.y; wreg[4*i+2] = w.z; wreg[4*i+3] = w.w;
        }
    }
    __shared__ __align__(16) u32 ys[32][64];
    for (int i = j; i < 32*64; i += 384) {
        const int sr = i >> 6, c = i & 63;
        ys[sr][c] = ((const u32*)(y1 + (size_t)(tile*32 + sr)*(nB*nH) + (size_t)b*nH))[c];
    }
    __syncthreads();
    f16* outp = (m == 0) ? qo : ((m == 1) ? ko : vo);
    for (int sl = 0; sl < 32; sl++) {
        float a0 = 0.f, a1 = 0.f;
        #pragma unroll
        for (int p = 0; p < 16; p++) {
            uint4 ya = ((const uint4*)ys[sl])[p];
            a0 = fdot2u(wreg[4*p+0], ya.x, a0); a1 = fdot2u(wreg[4*p+1], ya.y, a1);
            a0 = fdot2u(wreg[4*p+2], ya.z, a0); a1 = fdot2u(wreg[4*p+3], ya.w, a1);
        }
        outp[(size_t)b*(nS*nH) + (size_t)(tile*32 + sl)*nH + hp] = (f16)(a0 + a1);
    }
}

// ---------------- K4: attention core, 1 block per batch row ----------------
// scores -> softmax -> P@V -> proj(Pw) fused; writes hinit = h_final + proj
__global__ __launch_bounds__(256, 1) void attn_kernel(
    const f16* __restrict__ q, const f16* __restrict__ k, const f16* __restrict__ v,
    const float* __restrict__ Pw, const float* __restrict__ hf0,
    const float* __restrict__ hf1, float* __restrict__ hinit)
{
    const int b = blockIdx.x, j = threadIdx.x;
    __shared__ u32 ks[256*65];     // k rows, odd-word stride padding
    __shared__ u32 vTs[128*129];   // v transposed [h][s-pairs], padded
    __shared__ __align__(16) u32 qrow[64];
    __shared__ u32 p16[128];       // softmax weights fp16-packed
    __shared__ float red[8];
    __shared__ float pw_s[2][256];
    __shared__ float pvpart[2][128];

    const size_t bb = (size_t)b * (nS*nH);
    {
        const u32* src = (const u32*)(k + bb);
        for (int i = j; i < 256*64; i += 256) ks[(i>>6)*65 + (i&63)] = src[i];
    }
    {
        const u32* src = (const u32*)(v + bb);
        f16* vt = (f16*)vTs;
        for (int i = j; i < 256*64; i += 256) {
            const int s = i >> 6, c = i & 63;
            const f16x2 w = __builtin_bit_cast(f16x2, src[i]);
            vt[(2*c)  *258 + s] = w.x;
            vt[(2*c+1)*258 + s] = w.y;
        }
    }
    for (int i = j; i < 512; i += 256) ((float*)pw_s)[i] = Pw[i];
    float pj0 = 0.f, pj1 = 0.f;
    __syncthreads();

    const int lane = j & 63, wid = j >> 6;
    for (int s = 0; s < nS; s++) {
        if (j < 64) qrow[j] = ((const u32*)(q + bb + (size_t)s*nH))[j];
        __syncthreads();
        // score for key row t=j
        float s0 = 0.f, s1 = 0.f;
        #pragma unroll
        for (int p = 0; p < 16; p++) {
            uint4 qa = ((const uint4*)qrow)[p];
            s0 = fdot2u(ks[j*65 + 4*p+0], qa.x, s0);
            s1 = fdot2u(ks[j*65 + 4*p+1], qa.y, s1);
            s0 = fdot2u(ks[j*65 + 4*p+2], qa.z, s0);
            s1 = fdot2u(ks[j*65 + 4*p+3], qa.w, s1);
        }
        const float sc = s0 + s1;
        float mx = sc;
        #pragma unroll
        for (int msk = 32; msk; msk >>= 1) mx = fmaxf(mx, __shfl_xor(mx, msk));
        if (lane == 0) red[wid] = mx;
        __syncthreads();
        mx = fmaxf(fmaxf(red[0], red[1]), fmaxf(red[2], red[3]));
        const float e = __expf(sc - mx);
        float sm = e;
        #pragma unroll
        for (int msk = 32; msk; msk >>= 1) sm += __shfl_xor(sm, msk);
        if (lane == 0) red[4+wid] = sm;
        __syncthreads();
        sm = (red[4] + red[5]) + (red[6] + red[7]);
        ((f16*)p16)[j] = (f16)(e * __builtin_amdgcn_rcpf(sm));
        __syncthreads();
        // P @ V : thread (h, t-half)
        {
            const int h = j & 127, tb = (j >> 7) * 64;
            float a0 = 0.f, a1 = 0.f;
            #pragma unroll
            for (int p = 0; p < 64; p += 2) {
                a0 = fdot2u(vTs[h*129 + tb + p],     p16[tb + p],     a0);
                a1 = fdot2u(vTs[h*129 + tb + p + 1], p16[tb + p + 1], a1);
            }
            pvpart[j >> 7][h] = a0 + a1;
        }
        __syncthreads();
        if (j < 128) {
            const float ao = pvpart[0][j] + pvpart[1][j];
            pj0 += pw_s[0][s] * ao;
            pj1 += pw_s[1][s] * ao;
        }
    }
    if (j < 128) {
        hinit[(size_t)b*nH + j]                      = hf0[b*nH + j] + pj0;
        hinit[(size_t)(nB*nH) + (size_t)b*nH + j]    = hf1[b*nH + j] + pj1;
    }
}

// ---------------- K5: autoregressive decoder, persistent, 2 rows/block ----------------
// (512,1): see enc_layer comment. whh0[64]+w1[128]=192 u32 of weights/thread MUST
// be register-resident; the previous (512,2) 128-VGPR cap spilled them (2.2 GB
// scratch FETCH/dispatch, 2.9 ms, VALUBusy 19%).
__global__ __launch_bounds__(512, 1) void dec_kernel(
    const f16* __restrict__ WD0A, const f16* __restrict__ WD0B,
    const f16* __restrict__ WD1,  const f16* __restrict__ FCp,
    const float* __restrict__ BD0, const float* __restrict__ BD1,
    const float* __restrict__ fcb,
    const float* __restrict__ hinit, const float* __restrict__ cf0,
    const float* __restrict__ cf1, float* __restrict__ out)
{
    const int j = threadIdx.x, b0 = blockIdx.x * 2;
    u32 whh0[64], w1[128];
    {
        const uint4* wg = (const uint4*)(WD0B + (size_t)j * 128);
        #pragma unroll
        for (int i = 0; i < 16; i++) {
            uint4 w = wg[i];
            whh0[4*i+0] = w.x; whh0[4*i+1] = w.y; whh0[4*i+2] = w.z; whh0[4*i+3] = w.w;
        }
    }
    {
        const uint4* wg = (const uint4*)(WD1 + (size_t)j * 256);
        #pragma unroll
        for (int i = 0; i < 32; i++) {
            uint4 w = wg[i];
            w1[4*i+0] = w.x; w1[4*i+1] = w.y; w1[4*i+2] = w.z; w1[4*i+3] = w.w;
        }
    }
    const float bd0j = BD0[j], bd1j = BD1[j];
    const int gtype = j >> 7;

    __shared__ u32 wih0s[512*33];   // dec Wih0, padded row stride 33 words
    __shared__ u32 fcs[64*65];      // fc_W, padded row stride 65 words
    __shared__ __align__(16) u32 h0s[2][64], h1s[2][64];
    __shared__ __align__(16) u32 pr16[2][32];
    __shared__ float c0s[2][128], c1s[2][128];
    __shared__ float gact[2][512];

    {
        const u32* src = (const u32*)WD0A;
        for (int i = j; i < 512*32; i += 512) wih0s[(i>>5)*33 + (i&31)] = src[i];
    }
    {
        const u32* src = (const u32*)FCp;
        for (int i = j; i < 64*64; i += 512) fcs[(i>>6)*65 + (i&63)] = src[i];
    }
    if (j < 256) {
        const int r = j >> 7, kk = j & 127;
        c0s[r][kk] = cf0[(b0+r)*nH + kk];
        c1s[r][kk] = cf1[(b0+r)*nH + kk];
        ((f16*)h0s)[r*nH + kk] = (f16)hinit[(size_t)(b0+r)*nH + kk];
        ((f16*)h1s)[r*nH + kk] = (f16)hinit[(size_t)(nB*nH) + (size_t)(b0+r)*nH + kk];
    }
    if (j < 128) ((f16*)pr16)[j] = (f16)0.f;
    __syncthreads();

    for (int t = 0; t < nS; t++) {
        // ---- layer 0 gates ----
        float ax0 = bd0j, ax1 = bd0j, ah0 = 0.f, ah1 = 0.f;
        #pragma unroll
        for (int p = 0; p < 32; p++) {
            const u32 wa = wih0s[j*33 + p];
            ax0 = fdot2u(wa, pr16[0][p], ax0);
            ax1 = fdot2u(wa, pr16[1][p], ax1);
        }
        #pragma unroll
        for (int p = 0; p < 16; p++) {
            uint4 ha = ((const uint4*)h0s[0])[p], hb = ((const uint4*)h0s[1])[p];
            ah0 = fdot2u(whh0[4*p+0], ha.x, ah0); ah0 = fdot2u(whh0[4*p+1], ha.y, ah0);
            ah0 = fdot2u(whh0[4*p+2], ha.z, ah0); ah0 = fdot2u(whh0[4*p+3], ha.w, ah0);
            ah1 = fdot2u(whh0[4*p+0], hb.x, ah1); ah1 = fdot2u(whh0[4*p+1], hb.y, ah1);
            ah1 = fdot2u(whh0[4*p+2], hb.z, ah1); ah1 = fdot2u(whh0[4*p+3], hb.w, ah1);
        }
        {
            const float a0 = ax0 + ah0, a1 = ax1 + ah1;
            float v0, v1;
            if (gtype == 2) { v0 = tanh_f(a0); v1 = tanh_f(a1); }
            else            { v0 = sigm_f(a0); v1 = sigm_f(a1); }
            gact[0][j] = v0; gact[1][j] = v1;
        }
        __syncthreads();
        if (j < 256) {
            const int r = j >> 7, kk = j & 127;
            const float c2 = gact[r][128+kk] * c0s[r][kk] + gact[r][kk] * gact[r][256+kk];
            c0s[r][kk] = c2;
            ((f16*)h0s)[r*nH + kk] = (f16)(gact[r][384+kk] * tanh_f(c2));
        }
        __syncthreads();
        // ---- layer 1 gates ----
        float ux0 = bd1j, ux1 = bd1j, uh0 = 0.f, uh1 = 0.f;
        #pragma unroll
        for (int p = 0; p < 16; p++) {
            uint4 ha = ((const uint4*)h0s[0])[p], hb = ((const uint4*)h0s[1])[p];
            ux0 = fdot2u(w1[4*p+0], ha.x, ux0); ux0 = fdot2u(w1[4*p+1], ha.y, ux0);
            ux0 = fdot2u(w1[4*p+2], ha.z, ux0); ux0 = fdot2u(w1[4*p+3], ha.w, ux0);
            ux1 = fdot2u(w1[4*p+0], hb.x, ux1); ux1 = fdot2u(w1[4*p+1], hb.y, ux1);
            ux1 = fdot2u(w1[4*p+2], hb.z, ux1); ux1 = fdot2u(w1[4*p+3], hb.w, ux1);
        }
        #pragma unroll
        for (int p = 0; p < 16; p++) {
            uint4 ha = ((const uint4*)h1s[0])[p], hb = ((const uint4*)h1s[1])[p];
            uh0 = fdot2u(w1[64+4*p+0], ha.x, uh0); uh0 = fdot2u(w1[64+4*p+1], ha.y, uh0);
            uh0 = fdot2u(w1[64+4*p+2], ha.z, uh0); uh0 = fdot2u(w1[64+4*p+3], ha.w, uh0);
            uh1 = fdot2u(w1[64+4*p+0], hb.x, uh1); uh1 = fdot2u(w1[64+4*p+1], hb.y, uh1);
            uh1 = fdot2u(w1[64+4*p+2], hb.z, uh1); uh1 = fdot2u(w1[64+4*p+3], hb.w, uh1);
        }
        {
            const float a0 = ux0 + uh0, a1 = ux1 + uh1;
            float v0, v1;
            if (gtype == 2) { v0 = tanh_f(a0); v1 = tanh_f(a1); }
            else            { v0 = sigm_f(a0); v1 = sigm_f(a1); }
            gact[0][j] = v0; gact[1][j] = v1;
        }
        __syncthreads();
        if (j < 256) {
            const int r = j >> 7, kk = j & 127;
            const float c2 = gact[r][128+kk] * c1s[r][kk] + gact[r][kk] * gact[r][256+kk];
            c1s[r][kk] = c2;
            ((f16*)h1s)[r*nH + kk] = (f16)(gact[r][384+kk] * tanh_f(c2));
        }
        __syncthreads();
        // ---- fc + feedback ----
        if (j < 128) {
            const int r = j >> 6, d = j & 63;
            float a0 = fcb[d], a1 = 0.f;
            #pragma unroll
            for (int p = 0; p < 64; p += 2) {
                a0 = fdot2u(fcs[d*65 + p],     h1s[r][p],     a0);
                a1 = fdot2u(fcs[d*65 + p + 1], h1s[r][p + 1], a1);
            }
            const float pred = a0 + a1;
            out[(size_t)(b0+r)*(nS*nD) + (size_t)t*nD + d] = pred;
            ((f16*)pr16)[r*64 + d] = (f16)pred;
        }
        __syncthreads();
    }
}

// ---------------- launch ----------------
extern "C" void kernel_launch(void* const* d_in, const int* in_sizes, int n_in,
                              void* d_out, int out_size, void* d_ws, size_t ws_size,
                              hipStream_t stream)
{
    (void)in_sizes; (void)n_in; (void)out_size;
    if (ws_size < WS_NEED) return;   // workspace too small — cannot proceed

    const float* x      = (const float*)d_in[0];
    const float* eWih0  = (const float*)d_in[1];
    const float* eWhh0  = (const float*)d_in[2];
    const float* ebih0  = (const float*)d_in[3];
    const float* ebhh0  = (const float*)d_in[4];
    const float* eWih1  = (const float*)d_in[5];
    const float* eWhh1  = (const float*)d_in[6];
    const float* ebih1  = (const float*)d_in[7];
    const float* ebhh1  = (const float*)d_in[8];
    const float* dWih0  = (const float*)d_in[9];
    const float* dWhh0  = (const float*)d_in[10];
    const float* dbih0  = (const float*)d_in[11];
    const float* dbhh0  = (const float*)d_in[12];
    const float* dWih1  = (const float*)d_in[13];
    const float* dWhh1  = (const float*)d_in[14];
    const float* dbih1  = (const float*)d_in[15];
    const float* dbhh1  = (const float*)d_in[16];
    const float* fcW    = (const float*)d_in[17];
    const float* fcb    = (const float*)d_in[18];
    const float* Qw     = (const float*)d_in[19];
    const float* Kw     = (const float*)d_in[20];
    const float* Vw     = (const float*)d_in[21];
    const float* Pw     = (const float*)d_in[22];

    char* ws = (char*)d_ws;
    f16*   W0    = (f16*)(ws + OFF_W0);
    f16*   W1    = (f16*)(ws + OFF_W1);
    f16*   WD0A  = (f16*)(ws + OFF_WD0A);
    f16*   WD0B  = (f16*)(ws + OFF_WD0B);
    f16*   WD1   = (f16*)(ws + OFF_WD1);
    f16*   FCp   = (f16*)(ws + OFF_FC);
    f16*   QKVW  = (f16*)(ws + OFF_QKVW);
    float* B0f   = (float*)(ws + OFF_B0);
    float* B1f   = (float*)(ws + OFF_B1);
    float* BD0f  = (float*)(ws + OFF_BD0);
    float* BD1f  = (float*)(ws + OFF_BD1);
    float* HF0   = (float*)(ws + OFF_HF0);
    float* CF0   = (float*)(ws + OFF_CF0);
    float* HF1   = (float*)(ws + OFF_HF1);
    float* CF1   = (float*)(ws + OFF_CF1);
    float* HINIT = (float*)(ws + OFF_HINIT);
    f16*   Y0    = (f16*)(ws + OFF_Y0);
    f16*   Y1    = (f16*)(ws + OFF_Y1);
    f16*   Qb    = (f16*)(ws + OFF_Q);
    f16*   Kb    = (f16*)(ws + OFF_K);
    f16*   Vb    = (f16*)(ws + OFF_V);

    prep_kernel<<<dim3(64, 8), 256, 0, stream>>>(
        eWih0, eWhh0, ebih0, ebhh0, eWih1, eWhh1, ebih1, ebhh1,
        dWih0, dWhh0, dbih0, dbhh0, dWih1, dWhh1, dbih1, dbhh1,
        fcW, Qw, Kw, Vw,
        W0, W1, WD0A, WD0B, WD1, FCp, QKVW, B0f, B1f, BD0f, BD1f);

    enc_layer<64, true><<<256, 512, 0, stream>>>(W0, B0f, x, nullptr, Y0, HF0, CF0);
    enc_layer<128, false><<<256, 512, 0, stream>>>(W1, B1f, nullptr, Y0, Y1, HF1, CF1);
    qkv_kernel<<<dim3(512, 8), 384, 0, stream>>>(Y1, QKVW, Qb, Kb, Vb);
    attn_kernel<<<512, 256, 0, stream>>>(Qb, Kb, Vb, Pw, HF0, HF1, HINIT);
    dec_kernel<<<256, 512, 0, stream>>>(WD0A, WD0B, WD1, FCp, BD0f, BD1f, fcb,
                                        HINIT, CF0, CF1, (float*)d_out);
}

// Round 11
// 3913.353 us; speedup vs baseline: 1.2862x; 1.2855x over previous
//
#include <hip/hip_runtime.h>
#include <cstdint>
#include <cstddef>

typedef unsigned int u32;
typedef _Float16 f16;
typedef f16 f16x2 __attribute__((ext_vector_type(2)));

constexpr int nB = 512, nS = 256, nD = 64, nH = 128, nG = 512;

// ---------------- workspace layout (bytes) ----------------
constexpr size_t OFF_W0   = 0;                                   // [512][192] f16 enc0 Wih|Whh
constexpr size_t OFF_W1   = OFF_W0   + (size_t)512*192*2;        // [512][256] f16 enc1 Wih|Whh
constexpr size_t OFF_WD0A = OFF_W1   + (size_t)512*256*2;        // [512][64]  f16 dec Wih0
constexpr size_t OFF_WD0B = OFF_WD0A + (size_t)512*64*2;         // [512][128] f16 dec Whh0
constexpr size_t OFF_WD1  = OFF_WD0B + (size_t)512*128*2;        // [512][256] f16 dec Wih1|Whh1
constexpr size_t OFF_FC   = OFF_WD1  + (size_t)512*256*2;        // [64][128]  f16 fc_W
constexpr size_t OFF_QKVW = OFF_FC   + (size_t)64*128*2;         // [3][128][128] f16 Qw,Kw,Vw
constexpr size_t OFF_B0   = OFF_QKVW + (size_t)3*128*128*2;      // [512] f32 (bih+bhh)
constexpr size_t OFF_B1   = OFF_B0   + 512*4;
constexpr size_t OFF_BD0  = OFF_B1   + 512*4;
constexpr size_t OFF_BD1  = OFF_BD0  + 512*4;
constexpr size_t OFF_HF0  = OFF_BD1  + 512*4;                    // [B][H] f32 enc L0 final h
constexpr size_t OFF_CF0  = OFF_HF0  + (size_t)nB*nH*4;
constexpr size_t OFF_HF1  = OFF_CF0  + (size_t)nB*nH*4;
constexpr size_t OFF_CF1  = OFF_HF1  + (size_t)nB*nH*4;
constexpr size_t OFF_HINIT= OFF_CF1  + (size_t)nB*nH*4;          // [2][B][H] f32 (hfin + proj)
constexpr size_t OFF_Y0   = OFF_HINIT+ (size_t)2*nB*nH*4;        // [S][B][H] f16
constexpr size_t OFF_Y1   = OFF_Y0   + (size_t)nS*nB*nH*2;       // [S][B][H] f16
constexpr size_t OFF_Q    = OFF_Y1   + (size_t)nS*nB*nH*2;       // [B][S][H] f16
constexpr size_t OFF_K    = OFF_Q    + (size_t)nB*nS*nH*2;
constexpr size_t OFF_V    = OFF_K    + (size_t)nB*nS*nH*2;
constexpr size_t WS_NEED  = OFF_V    + (size_t)nB*nS*nH*2;       // ~170 MB

// ---------------- helpers ----------------
__device__ __forceinline__ float fdot2u(u32 w, u32 x, float acc) {
#if defined(__has_builtin)
#if __has_builtin(__builtin_amdgcn_fdot2)
    return __builtin_amdgcn_fdot2(__builtin_bit_cast(f16x2, w),
                                  __builtin_bit_cast(f16x2, x), acc, false);
#else
    const f16x2 a = __builtin_bit_cast(f16x2, w), b = __builtin_bit_cast(f16x2, x);
    return acc + (float)a.x * (float)b.x + (float)a.y * (float)b.y;
#endif
#else
    const f16x2 a = __builtin_bit_cast(f16x2, w), b = __builtin_bit_cast(f16x2, x);
    return acc + (float)a.x * (float)b.x + (float)a.y * (float)b.y;
#endif
}

__device__ __forceinline__ float sigm_f(float x) {
    return __builtin_amdgcn_rcpf(1.0f + __expf(-x));
}
__device__ __forceinline__ float tanh_f(float x) {
    // 1 - 2/(e^{2x}+1); exp overflow/underflow saturate correctly to +-1
    return 1.0f - 2.0f * __builtin_amdgcn_rcpf(__expf(2.0f * x) + 1.0f);
}

// ---------------- K0: weight pack/convert (fp32 -> fp16, bias fuse) ----------------
__global__ void prep_kernel(
    const float* __restrict__ Wih0, const float* __restrict__ Whh0,
    const float* __restrict__ bih0, const float* __restrict__ bhh0,
    const float* __restrict__ Wih1, const float* __restrict__ Whh1,
    const float* __restrict__ bih1, const float* __restrict__ bhh1,
    const float* __restrict__ dWih0, const float* __restrict__ dWhh0,
    const float* __restrict__ dbih0, const float* __restrict__ dbhh0,
    const float* __restrict__ dWih1, const float* __restrict__ dWhh1,
    const float* __restrict__ dbih1, const float* __restrict__ dbhh1,
    const float* __restrict__ fcW, const float* __restrict__ Qw,
    const float* __restrict__ Kw,  const float* __restrict__ Vw,
    f16* __restrict__ W0, f16* __restrict__ W1, f16* __restrict__ WD0A,
    f16* __restrict__ WD0B, f16* __restrict__ WD1, f16* __restrict__ FCp,
    f16* __restrict__ QKVW, float* __restrict__ B0, float* __restrict__ B1,
    float* __restrict__ BD0, float* __restrict__ BD1)
{
    const int sec = blockIdx.y;
    const int idx0 = blockIdx.x * blockDim.x + threadIdx.x;
    const int stride = gridDim.x * blockDim.x;
    switch (sec) {
    case 0: for (int i = idx0; i < 512*192; i += stride) {
                int g = i / 192, c = i % 192;
                W0[i] = (f16)(c < 64 ? Wih0[g*64 + c] : Whh0[g*128 + (c-64)]);
            } break;
    case 1: for (int i = idx0; i < 512*256; i += stride) {
                int g = i >> 8, c = i & 255;
                W1[i] = (f16)(c < 128 ? Wih1[g*128 + c] : Whh1[g*128 + (c-128)]);
            } break;
    case 2: for (int i = idx0; i < 512*64; i += stride) WD0A[i] = (f16)dWih0[i]; break;
    case 3: for (int i = idx0; i < 512*128; i += stride) WD0B[i] = (f16)dWhh0[i]; break;
    case 4: for (int i = idx0; i < 512*256; i += stride) {
                int g = i >> 8, c = i & 255;
                WD1[i] = (f16)(c < 128 ? dWih1[g*128 + c] : dWhh1[g*128 + (c-128)]);
            } break;
    case 5: for (int i = idx0; i < 64*128; i += stride) FCp[i] = (f16)fcW[i]; break;
    case 6: for (int i = idx0; i < 3*128*128; i += stride) {
                int m = i >> 14, r = i & 16383;
                const float* src = (m == 0) ? Qw : ((m == 1) ? Kw : Vw);
                QKVW[i] = (f16)src[r];
            } break;
    case 7: for (int i = idx0; i < 2048; i += stride) {
                int w = i >> 9, g = i & 511;
                if      (w == 0) B0[g]  = bih0[g]  + bhh0[g];
                else if (w == 1) B1[g]  = bih1[g]  + bhh1[g];
                else if (w == 2) BD0[g] = dbih0[g] + dbhh0[g];
                else             BD1[g] = dbih1[g] + dbhh1[g];
            } break;
    }
}

// ---------------- K1/K2: encoder LSTM layer, persistent, 2 batch rows/block ----------------
// 256 blocks x 512 threads. Thread j owns gate column j (weights in VGPRs, fp16x2).
// ATTRIBUTE EXPERIMENT (R8): __launch_bounds__(512,{1,2}) both compiled at VGPR=128
// (default 1024-thread budget) -> spill. These backend-native attributes request
// waves_per_eu(2,2) -> VGPR cap 512/2 = 256/wave. If the bench shows enc VGPR>128,
// attributes work; if still 128, stop fighting the allocator and split enc like dec.
template<int KIN, bool FIRST>
__global__ __attribute__((amdgpu_flat_work_group_size(512, 512), amdgpu_waves_per_eu(2, 2)))
void enc_layer(
    const f16* __restrict__ Wpack, const float* __restrict__ bias,
    const float* __restrict__ xf32, const f16* __restrict__ xf16,
    f16* __restrict__ yout, float* __restrict__ hfin, float* __restrict__ cfin)
{
    constexpr int KP = KIN + nH;       // halfs per weight row
    constexpr int NP = KP / 2;         // u32 per row
    const int j  = threadIdx.x;
    const int b0 = blockIdx.x * 2;
    u32 wreg[NP];
    {
        const uint4* wg = (const uint4*)(Wpack + (size_t)j * KP);
        #pragma unroll
        for (int i = 0; i < NP/4; i++) {
            uint4 w = wg[i];
            wreg[4*i+0] = w.x; wreg[4*i+1] = w.y; wreg[4*i+2] = w.z; wreg[4*i+3] = w.w;
        }
    }
    const float bj = bias[j];
    const int gtype = j >> 7;          // 0:i 1:f 2:g 3:o

    __shared__ __align__(16) u32 xs[2][KIN/2];
    __shared__ __align__(16) u32 hs[2][nH/2];
    __shared__ float cs[2][nH];
    __shared__ float gact[2][nG];

    if (j < 256) { ((f16*)hs)[j] = (f16)0.f; ((float*)cs)[j] = 0.f; }
    __syncthreads();

    for (int t = 0; t < nS; t++) {
        // stage input (2 rows)
        if (j < 128) {
            if constexpr (FIRST) {           // x: [B][S][D] fp32 -> fp16
                const int r = j >> 6, d = j & 63;
                ((f16*)xs)[j] = (f16)xf32[(size_t)(b0+r)*(nS*nD) + (size_t)t*nD + d];
            } else {                         // y0: [S][B][H] fp16, u32 pair loads
                const int r = j >> 6, c = j & 63;
                ((u32*)xs)[j] = ((const u32*)(xf16 + (size_t)t*(nB*nH) + (size_t)(b0+r)*nH))[c];
            }
        }
        __syncthreads();

        float ax0 = bj, ax1 = bj, ah0 = 0.f, ah1 = 0.f;
        #pragma unroll
        for (int p = 0; p < KIN/8; p++) {
            uint4 x0 = ((const uint4*)xs[0])[p], x1 = ((const uint4*)xs[1])[p];
            ax0 = fdot2u(wreg[4*p+0], x0.x, ax0); ax0 = fdot2u(wreg[4*p+1], x0.y, ax0);
            ax0 = fdot2u(wreg[4*p+2], x0.z, ax0); ax0 = fdot2u(wreg[4*p+3], x0.w, ax0);
            ax1 = fdot2u(wreg[4*p+0], x1.x, ax1); ax1 = fdot2u(wreg[4*p+1], x1.y, ax1);
            ax1 = fdot2u(wreg[4*p+2], x1.z, ax1); ax1 = fdot2u(wreg[4*p+3], x1.w, ax1);
        }
        #pragma unroll
        for (int p = 0; p < nH/8; p++) {
            uint4 h0 = ((const uint4*)hs[0])[p], h1 = ((const uint4*)hs[1])[p];
            ah0 = fdot2u(wreg[KIN/2+4*p+0], h0.x, ah0); ah0 = fdot2u(wreg[KIN/2+4*p+1], h0.y, ah0);
            ah0 = fdot2u(wreg[KIN/2+4*p+2], h0.z, ah0); ah0 = fdot2u(wreg[KIN/2+4*p+3], h0.w, ah0);
            ah1 = fdot2u(wreg[KIN/2+4*p+0], h1.x, ah1); ah1 = fdot2u(wreg[KIN/2+4*p+1], h1.y, ah1);
            ah1 = fdot2u(wreg[KIN/2+4*p+2], h1.z, ah1); ah1 = fdot2u(wreg[KIN/2+4*p+3], h1.w, ah1);
        }
        {
            const float a0 = ax0 + ah0, a1 = ax1 + ah1;
            float v0, v1;
            if (gtype == 2) { v0 = tanh_f(a0); v1 = tanh_f(a1); }
            else            { v0 = sigm_f(a0); v1 = sigm_f(a1); }
            gact[0][j] = v0; gact[1][j] = v1;
        }
        __syncthreads();
        if (j < 256) {
            const int r = j >> 7, kk = j & 127;
            const float gi = gact[r][kk], gf = gact[r][128+kk];
            const float gg = gact[r][256+kk], go = gact[r][384+kk];
            const float c2 = gf * cs[r][kk] + gi * gg;
            const float h2 = go * tanh_f(c2);
            cs[r][kk] = c2;
            ((f16*)hs)[r*nH + kk] = (f16)h2;
            yout[(size_t)t*(nB*nH) + (size_t)(b0+r)*nH + kk] = (f16)h2;
            if (t == nS-1) { hfin[(b0+r)*nH + kk] = h2; cfin[(b0+r)*nH + kk] = c2; }
        }
        __syncthreads();
    }
}

// ---------------- K3: q,k,v = y1 @ {Qw,Kw,Vw}^T ----------------
// grid (512 b, 8 s-tiles) x 384 thr; thread = (m in {q,k,v}, out column hp)
__global__ __attribute__((amdgpu_flat_work_group_size(384, 384), amdgpu_waves_per_eu(2)))
void qkv_kernel(
    const f16* __restrict__ y1, const f16* __restrict__ W,
    f16* __restrict__ qo, f16* __restrict__ ko, f16* __restrict__ vo)
{
    const int b = blockIdx.x, tile = blockIdx.y, j = threadIdx.x;
    const int m = j >> 7, hp = j & 127;
    u32 wreg[64];
    {
        const uint4* wg = (const uint4*)(W + ((size_t)(m*128 + hp)) * nH);
        #pragma unroll
        for (int i = 0; i < 16; i++) {
            uint4 w = wg[i];
            wreg[4*i+0] = w.x; wreg[4*i+1] = w.y; wreg[4*i+2] = w.z; wreg[4*i+3] = w.w;
        }
    }
    __shared__ __align__(16) u32 ys[32][64];
    for (int i = j; i < 32*64; i += 384) {
        const int sr = i >> 6, c = i & 63;
        ys[sr][c] = ((const u32*)(y1 + (size_t)(tile*32 + sr)*(nB*nH) + (size_t)b*nH))[c];
    }
    __syncthreads();
    f16* outp = (m == 0) ? qo : ((m == 1) ? ko : vo);
    for (int sl = 0; sl < 32; sl++) {
        float a0 = 0.f, a1 = 0.f;
        #pragma unroll
        for (int p = 0; p < 16; p++) {
            uint4 ya = ((const uint4*)ys[sl])[p];
            a0 = fdot2u(wreg[4*p+0], ya.x, a0); a1 = fdot2u(wreg[4*p+1], ya.y, a1);
            a0 = fdot2u(wreg[4*p+2], ya.z, a0); a1 = fdot2u(wreg[4*p+3], ya.w, a1);
        }
        outp[(size_t)b*(nS*nH) + (size_t)(tile*32 + sl)*nH + hp] = (f16)(a0 + a1);
    }
}

// ---------------- K4: attention core, 1 block per batch row ----------------
// scores -> softmax -> P@V -> proj(Pw) fused; writes hinit = h_final + proj
__global__ __attribute__((amdgpu_flat_work_group_size(256, 256), amdgpu_waves_per_eu(1)))
void attn_kernel(
    const f16* __restrict__ q, const f16* __restrict__ k, const f16* __restrict__ v,
    const float* __restrict__ Pw, const float* __restrict__ hf0,
    const float* __restrict__ hf1, float* __restrict__ hinit)
{
    const int b = blockIdx.x, j = threadIdx.x;
    __shared__ u32 ks[256*65];     // k rows, odd-word stride padding
    __shared__ u32 vTs[128*129];   // v transposed [h][s-pairs], padded
    __shared__ __align__(16) u32 qrow[64];
    __shared__ u32 p16[128];       // softmax weights fp16-packed
    __shared__ float red[8];
    __shared__ float pw_s[2][256];
    __shared__ float pvpart[2][128];

    const size_t bb = (size_t)b * (nS*nH);
    {
        const u32* src = (const u32*)(k + bb);
        for (int i = j; i < 256*64; i += 256) ks[(i>>6)*65 + (i&63)] = src[i];
    }
    {
        const u32* src = (const u32*)(v + bb);
        f16* vt = (f16*)vTs;
        for (int i = j; i < 256*64; i += 256) {
            const int s = i >> 6, c = i & 63;
            const f16x2 w = __builtin_bit_cast(f16x2, src[i]);
            vt[(2*c)  *258 + s] = w.x;
            vt[(2*c+1)*258 + s] = w.y;
        }
    }
    for (int i = j; i < 512; i += 256) ((float*)pw_s)[i] = Pw[i];
    float pj0 = 0.f, pj1 = 0.f;
    __syncthreads();

    const int lane = j & 63, wid = j >> 6;
    for (int s = 0; s < nS; s++) {
        if (j < 64) qrow[j] = ((const u32*)(q + bb + (size_t)s*nH))[j];
        __syncthreads();
        // score for key row t=j
        float s0 = 0.f, s1 = 0.f;
        #pragma unroll
        for (int p = 0; p < 16; p++) {
            uint4 qa = ((const uint4*)qrow)[p];
            s0 = fdot2u(ks[j*65 + 4*p+0], qa.x, s0);
            s1 = fdot2u(ks[j*65 + 4*p+1], qa.y, s1);
            s0 = fdot2u(ks[j*65 + 4*p+2], qa.z, s0);
            s1 = fdot2u(ks[j*65 + 4*p+3], qa.w, s1);
        }
        const float sc = s0 + s1;
        float mx = sc;
        #pragma unroll
        for (int msk = 32; msk; msk >>= 1) mx = fmaxf(mx, __shfl_xor(mx, msk));
        if (lane == 0) red[wid] = mx;
        __syncthreads();
        mx = fmaxf(fmaxf(red[0], red[1]), fmaxf(red[2], red[3]));
        const float e = __expf(sc - mx);
        float sm = e;
        #pragma unroll
        for (int msk = 32; msk; msk >>= 1) sm += __shfl_xor(sm, msk);
        if (lane == 0) red[4+wid] = sm;
        __syncthreads();
        sm = (red[4] + red[5]) + (red[6] + red[7]);
        ((f16*)p16)[j] = (f16)(e * __builtin_amdgcn_rcpf(sm));
        __syncthreads();
        // P @ V : thread (h, t-half)
        {
            const int h = j & 127, tb = (j >> 7) * 64;
            float a0 = 0.f, a1 = 0.f;
            #pragma unroll
            for (int p = 0; p < 64; p += 2) {
                a0 = fdot2u(vTs[h*129 + tb + p],     p16[tb + p],     a0);
                a1 = fdot2u(vTs[h*129 + tb + p + 1], p16[tb + p + 1], a1);
            }
            pvpart[j >> 7][h] = a0 + a1;
        }
        __syncthreads();
        if (j < 128) {
            const float ao = pvpart[0][j] + pvpart[1][j];
            pj0 += pw_s[0][s] * ao;
            pj1 += pw_s[1][s] * ao;
        }
    }
    if (j < 128) {
        hinit[(size_t)b*nH + j]                      = hf0[b*nH + j] + pj0;
        hinit[(size_t)(nB*nH) + (size_t)b*nH + j]    = hf1[b*nH + j] + pj1;
    }
}

// ---------------- K5: autoregressive decoder v2 — allocator-agnostic split ----------------
// R8 redesign: R0/R6 proved the backend pins VGPR=128 (launch_bounds hints dropped),
// spilling the 192-u32/thread weight set -> 2.2 GB scratch/dispatch = 2.9 ms.
// v2 fits 128 VGPRs BY CONSTRUCTION: 1024 threads = gate j (0..511) x half h (0..1).
// Each thread holds HALF the gate's weights: whh0h[32] (Whh0 k-half) + w1h[64]
// (h=0: Wih1 row, h=1: Whh1 row) = 96 u32. Wih0 stays in LDS (stride 33 = 2-way, free).
// Halves meet in LDS part[h][row][gate]; activation phase is 1024-wide (1/thread).
// ~224 fdot2/thread/step; 16 waves/CU.
__global__ __attribute__((amdgpu_flat_work_group_size(1024, 1024), amdgpu_waves_per_eu(4, 4)))
void dec_kernel(
    const f16* __restrict__ WD0A, const f16* __restrict__ WD0B,
    const f16* __restrict__ WD1,  const f16* __restrict__ FCp,
    const float* __restrict__ BD0, const float* __restrict__ BD1,
    const float* __restrict__ fcb,
    const float* __restrict__ hinit, const float* __restrict__ cf0,
    const float* __restrict__ cf1, float* __restrict__ out)
{
    const int tid = threadIdx.x;
    const int j = tid & 511;          // gate
    const int h = tid >> 9;           // K-half (wave-uniform: waves 0-7 h=0, 8-15 h=1)
    const int b0 = blockIdx.x * 2;

    u32 whh0h[32], w1h[64];
    {   // Whh0 row j, k-halfs h*64..h*64+63  (32 u32)
        const uint4* wg = (const uint4*)(WD0B + (size_t)j * 128 + (size_t)h * 64);
        #pragma unroll
        for (int i = 0; i < 8; i++) {
            uint4 w = wg[i];
            whh0h[4*i+0] = w.x; whh0h[4*i+1] = w.y; whh0h[4*i+2] = w.z; whh0h[4*i+3] = w.w;
        }
    }
    {   // W1 row j: h=0 -> Wih1 part (input h0s), h=1 -> Whh1 part (input h1s)  (64 u32)
        const uint4* wg = (const uint4*)(WD1 + (size_t)j * 256 + (size_t)h * 128);
        #pragma unroll
        for (int i = 0; i < 16; i++) {
            uint4 w = wg[i];
            w1h[4*i+0] = w.x; w1h[4*i+1] = w.y; w1h[4*i+2] = w.z; w1h[4*i+3] = w.w;
        }
    }
    const float b0j = (h == 0) ? BD0[j] : 0.f;
    const float b1j = (h == 0) ? BD1[j] : 0.f;

    __shared__ u32 wih0s[512*33];     // dec Wih0, padded stride 33 words (2-way = free)
    __shared__ u32 fcs[64*65];        // fc_W, padded stride 65 words
    __shared__ __align__(16) u32 h0s[2][64], h1s[2][64];
    __shared__ __align__(16) u32 pr16[2][32];
    __shared__ float c0s[2][128], c1s[2][128];
    __shared__ float part[2][2][512]; // [half][row][gate] partial gate sums
    __shared__ float gact[2][512];

    {
        const u32* src = (const u32*)WD0A;
        for (int i = tid; i < 512*32; i += 1024) wih0s[(i>>5)*33 + (i&31)] = src[i];
    }
    {
        const u32* src = (const u32*)FCp;
        for (int i = tid; i < 64*64; i += 1024) fcs[(i>>6)*65 + (i&63)] = src[i];
    }
    if (tid < 256) {
        const int r = tid >> 7, kk = tid & 127;
        c0s[r][kk] = cf0[(b0+r)*nH + kk];
        c1s[r][kk] = cf1[(b0+r)*nH + kk];
        ((f16*)h0s)[r*nH + kk] = (f16)hinit[(size_t)(b0+r)*nH + kk];
        ((f16*)h1s)[r*nH + kk] = (f16)hinit[(size_t)(nB*nH) + (size_t)(b0+r)*nH + kk];
    }
    if (tid < 128) ((f16*)pr16)[tid] = (f16)0.f;
    __syncthreads();

    // L1 input select for this half: h=0 reads h0s (Wih1 path), h=1 reads h1s (Whh1 path)
    const uint4* l1s0 = (const uint4*)(h ? h1s[0] : h0s[0]);
    const uint4* l1s1 = (const uint4*)(h ? h1s[1] : h0s[1]);

    for (int t = 0; t < nS; t++) {
        // ---- layer 0 partials: x-part (16 u32 from LDS) + h-part (32 u32 regs) ----
        {
            float a0 = b0j, a1 = b0j;
            #pragma unroll
            for (int q = 0; q < 4; q++) {
                uint4 x0 = ((const uint4*)pr16[0])[h*4 + q];
                uint4 x1 = ((const uint4*)pr16[1])[h*4 + q];
                const int wb = j*33 + h*16 + 4*q;
                const u32 wa = wih0s[wb+0], wbw = wih0s[wb+1], wc = wih0s[wb+2], wd = wih0s[wb+3];
                a0 = fdot2u(wa, x0.x, a0); a0 = fdot2u(wbw, x0.y, a0);
                a0 = fdot2u(wc, x0.z, a0); a0 = fdot2u(wd, x0.w, a0);
                a1 = fdot2u(wa, x1.x, a1); a1 = fdot2u(wbw, x1.y, a1);
                a1 = fdot2u(wc, x1.z, a1); a1 = fdot2u(wd, x1.w, a1);
            }
            #pragma unroll
            for (int q = 0; q < 8; q++) {
                uint4 ha = ((const uint4*)h0s[0])[h*8 + q];
                uint4 hb = ((const uint4*)h0s[1])[h*8 + q];
                a0 = fdot2u(whh0h[4*q+0], ha.x, a0); a0 = fdot2u(whh0h[4*q+1], ha.y, a0);
                a0 = fdot2u(whh0h[4*q+2], ha.z, a0); a0 = fdot2u(whh0h[4*q+3], ha.w, a0);
                a1 = fdot2u(whh0h[4*q+0], hb.x, a1); a1 = fdot2u(whh0h[4*q+1], hb.y, a1);
                a1 = fdot2u(whh0h[4*q+2], hb.z, a1); a1 = fdot2u(whh0h[4*q+3], hb.w, a1);
            }
            part[h][0][j] = a0; part[h][1][j] = a1;
        }
        __syncthreads();
        {   // reduce + activate: one (row, gate) per thread
            const int r = tid >> 9, jj = tid & 511;
            const float a = part[0][r][jj] + part[1][r][jj];
            gact[r][jj] = ((jj >> 7) == 2) ? tanh_f(a) : sigm_f(a);
        }
        __syncthreads();
        if (tid < 256) {
            const int r = tid >> 7, kk = tid & 127;
            const float c2 = gact[r][128+kk] * c0s[r][kk] + gact[r][kk] * gact[r][256+kk];
            c0s[r][kk] = c2;
            ((f16*)h0s)[r*nH + kk] = (f16)(gact[r][384+kk] * tanh_f(c2));
        }
        __syncthreads();
        // ---- layer 1 partials: h=0: Wih1 x h0s; h=1: Whh1 x h1s (64 u32 each) ----
        {
            float u0 = b1j, u1 = b1j;
            #pragma unroll
            for (int q = 0; q < 16; q++) {
                uint4 ha = l1s0[q], hb = l1s1[q];
                u0 = fdot2u(w1h[4*q+0], ha.x, u0); u0 = fdot2u(w1h[4*q+1], ha.y, u0);
                u0 = fdot2u(w1h[4*q+2], ha.z, u0); u0 = fdot2u(w1h[4*q+3], ha.w, u0);
                u1 = fdot2u(w1h[4*q+0], hb.x, u1); u1 = fdot2u(w1h[4*q+1], hb.y, u1);
                u1 = fdot2u(w1h[4*q+2], hb.z, u1); u1 = fdot2u(w1h[4*q+3], hb.w, u1);
            }
            part[h][0][j] = u0; part[h][1][j] = u1;
        }
        __syncthreads();
        {
            const int r = tid >> 9, jj = tid & 511;
            const float a = part[0][r][jj] + part[1][r][jj];
            gact[r][jj] = ((jj >> 7) == 2) ? tanh_f(a) : sigm_f(a);
        }
        __syncthreads();
        if (tid < 256) {
            const int r = tid >> 7, kk = tid & 127;
            const float c2 = gact[r][128+kk] * c1s[r][kk] + gact[r][kk] * gact[r][256+kk];
            c1s[r][kk] = c2;
            ((f16*)h1s)[r*nH + kk] = (f16)(gact[r][384+kk] * tanh_f(c2));
        }
        __syncthreads();
        // ---- fc + feedback ----
        if (tid < 128) {
            const int r = tid >> 6, d = tid & 63;
            float a0 = fcb[d], a1 = 0.f;
            #pragma unroll
            for (int p = 0; p < 64; p += 2) {
                a0 = fdot2u(fcs[d*65 + p],     h1s[r][p],     a0);
                a1 = fdot2u(fcs[d*65 + p + 1], h1s[r][p + 1], a1);
            }
            const float pred = a0 + a1;
            out[(size_t)(b0+r)*(nS*nD) + (size_t)t*nD + d] = pred;
            ((f16*)pr16)[r*64 + d] = (f16)pred;
        }
        __syncthreads();
    }
}

// ---------------- launch ----------------
extern "C" void kernel_launch(void* const* d_in, const int* in_sizes, int n_in,
                              void* d_out, int out_size, void* d_ws, size_t ws_size,
                              hipStream_t stream)
{
    (void)in_sizes; (void)n_in; (void)out_size;
    if (ws_size < WS_NEED) return;   // workspace too small — cannot proceed

    const float* x      = (const float*)d_in[0];
    const float* eWih0  = (const float*)d_in[1];
    const float* eWhh0  = (const float*)d_in[2];
    const float* ebih0  = (const float*)d_in[3];
    const float* ebhh0  = (const float*)d_in[4];
    const float* eWih1  = (const float*)d_in[5];
    const float* eWhh1  = (const float*)d_in[6];
    const float* ebih1  = (const float*)d_in[7];
    const float* ebhh1  = (const float*)d_in[8];
    const float* dWih0  = (const float*)d_in[9];
    const float* dWhh0  = (const float*)d_in[10];
    const float* dbih0  = (const float*)d_in[11];
    const float* dbhh0  = (const float*)d_in[12];
    const float* dWih1  = (const float*)d_in[13];
    const float* dWhh1  = (const float*)d_in[14];
    const float* dbih1  = (const float*)d_in[15];
    const float* dbhh1  = (const float*)d_in[16];
    const float* fcW    = (const float*)d_in[17];
    const float* fcb    = (const float*)d_in[18];
    const float* Qw     = (const float*)d_in[19];
    const float* Kw     = (const float*)d_in[20];
    const float* Vw     = (const float*)d_in[21];
    const float* Pw     = (const float*)d_in[22];

    char* ws = (char*)d_ws;
    f16*   W0    = (f16*)(ws + OFF_W0);
    f16*   W1    = (f16*)(ws + OFF_W1);
    f16*   WD0A  = (f16*)(ws + OFF_WD0A);
    f16*   WD0B  = (f16*)(ws + OFF_WD0B);
    f16*   WD1   = (f16*)(ws + OFF_WD1);
    f16*   FCp   = (f16*)(ws + OFF_FC);
    f16*   QKVW  = (f16*)(ws + OFF_QKVW);
    float* B0f   = (float*)(ws + OFF_B0);
    float* B1f   = (float*)(ws + OFF_B1);
    float* BD0f  = (float*)(ws + OFF_BD0);
    float* BD1f  = (float*)(ws + OFF_BD1);
    float* HF0   = (float*)(ws + OFF_HF0);
    float* CF0   = (float*)(ws + OFF_CF0);
    float* HF1   = (float*)(ws + OFF_HF1);
    float* CF1   = (float*)(ws + OFF_CF1);
    float* HINIT = (float*)(ws + OFF_HINIT);
    f16*   Y0    = (f16*)(ws + OFF_Y0);
    f16*   Y1    = (f16*)(ws + OFF_Y1);
    f16*   Qb    = (f16*)(ws + OFF_Q);
    f16*   Kb    = (f16*)(ws + OFF_K);
    f16*   Vb    = (f16*)(ws + OFF_V);

    prep_kernel<<<dim3(64, 8), 256, 0, stream>>>(
        eWih0, eWhh0, ebih0, ebhh0, eWih1, eWhh1, ebih1, ebhh1,
        dWih0, dWhh0, dbih0, dbhh0, dWih1, dWhh1, dbih1, dbhh1,
        fcW, Qw, Kw, Vw,
        W0, W1, WD0A, WD0B, WD1, FCp, QKVW, B0f, B1f, BD0f, BD1f);

    enc_layer<64, true><<<256, 512, 0, stream>>>(W0, B0f, x, nullptr, Y0, HF0, CF0);
    enc_layer<128, false><<<256, 512, 0, stream>>>(W1, B1f, nullptr, Y0, Y1, HF1, CF1);
    qkv_kernel<<<dim3(512, 8), 384, 0, stream>>>(Y1, QKVW, Qb, Kb, Vb);
    attn_kernel<<<512, 256, 0, stream>>>(Qb, Kb, Vb, Pw, HF0, HF1, HINIT);
    dec_kernel<<<256, 1024, 0, stream>>>(WD0A, WD0B, WD1, FCp, BD0f, BD1f, fcb,
                                         HINIT, CF0, CF1, (float*)d_out);
}